// Round 2
// baseline (36381.931 us; speedup 1.0000x reference)
//
#include <hip/hip_runtime.h>
#include <math.h>

#define BB 128
#define TT 256
#define DD 512
#define HH 1024
#define G4H 4096
#define CO 7

// ------------------------------------------------------------------
// GEMM: C[r][N] = Arow(r) . W[n][:] + b0[n] + b1[n]
// Row mapping: Arow(r) = A + (r>>lt)*sOut + (r&((1<<lt)-1))*sIn
// (lets us read x's [b][t][d] layout chunk-wise without a transpose)
// 64x64 tile, K-tile 16, 256 threads, 4x4 acc per thread.
// rows % 64 == 0, N % 64 == 0, K % 16 == 0.
// ------------------------------------------------------------------
__global__ __launch_bounds__(256)
void gemm_bias(const float* __restrict__ A, long long sOut, long long sIn, int lt,
               const float* __restrict__ W,
               const float* __restrict__ b0, const float* __restrict__ b1,
               float* __restrict__ C, int N, int K) {
  __shared__ float as[16][64];
  __shared__ float wsh[16][64];
  const int tid = threadIdx.x;
  const int bm = blockIdx.y << 6;
  const int bn = blockIdx.x << 6;
  const int tr = (tid >> 4) << 2;   // 0..60 step 4
  const int tc = (tid & 15) << 2;   // 0..60 step 4
  const int lrow = tid >> 2;        // 0..63
  const int lk4 = (tid & 3) << 2;   // 0,4,8,12
  const int msk = (1 << lt) - 1;
  const int r = bm + lrow;
  const float* ap = A + (size_t)(r >> lt) * sOut + (size_t)(r & msk) * sIn + lk4;
  const float* wp = W + (size_t)(bn + lrow) * K + lk4;
  float acc[4][4] = {};
  for (int k0 = 0; k0 < K; k0 += 16) {
    const float4 av = *(const float4*)(ap + k0);
    const float4 wv = *(const float4*)(wp + k0);
    __syncthreads();
    as[lk4 + 0][lrow] = av.x; as[lk4 + 1][lrow] = av.y;
    as[lk4 + 2][lrow] = av.z; as[lk4 + 3][lrow] = av.w;
    wsh[lk4 + 0][lrow] = wv.x; wsh[lk4 + 1][lrow] = wv.y;
    wsh[lk4 + 2][lrow] = wv.z; wsh[lk4 + 3][lrow] = wv.w;
    __syncthreads();
#pragma unroll
    for (int k = 0; k < 16; ++k) {
      const float4 a = *(const float4*)&as[k][tr];
      const float4 b = *(const float4*)&wsh[k][tc];
      acc[0][0] += a.x * b.x; acc[0][1] += a.x * b.y; acc[0][2] += a.x * b.z; acc[0][3] += a.x * b.w;
      acc[1][0] += a.y * b.x; acc[1][1] += a.y * b.y; acc[1][2] += a.y * b.z; acc[1][3] += a.y * b.w;
      acc[2][0] += a.z * b.x; acc[2][1] += a.z * b.y; acc[2][2] += a.z * b.z; acc[2][3] += a.z * b.w;
      acc[3][0] += a.w * b.x; acc[3][1] += a.w * b.y; acc[3][2] += a.w * b.z; acc[3][3] += a.w * b.w;
    }
  }
  const float* bp0 = b0 + bn + tc;
  const float* bp1 = b1 + bn + tc;
#pragma unroll
  for (int i = 0; i < 4; ++i) {
    float* cp = C + (size_t)(bm + tr + i) * N + bn + tc;
#pragma unroll
    for (int j = 0; j < 4; ++j) cp[j] = acc[i][j] + bp0[j] + bp1[j];
  }
}

// ------------------------------------------------------------------
// Fused per-timestep kernel: gates = gx[b] + h_prev @ whh^T, then the
// LSTM cell, writing c (in place) and h_next.
// Each WG: 16 batch rows x 32 j-cols x all 4 gates.
// grid = (HH/32 = 32, BB/16 = 8) = 256 WGs, 256 threads each.
// gx row b at gx + b*gxstride (gates j, H+j, 2H+j, 3H+j within row).
// h_prev row b at hprev + b*pstride (pstride 0 => broadcast zero row).
// ------------------------------------------------------------------
__global__ __launch_bounds__(256)
void lstm_step(const float* __restrict__ gx, long long gxstride,
               const float* __restrict__ whh,
               const float* __restrict__ hprev, long long pstride,
               float* __restrict__ hnext, long long nstride,
               float* __restrict__ cbuf) {
  __shared__ float hs[32][16];       // hs[k][row]   (transposed h tile)
  __shared__ float wsm[32][4][32];   // wsm[k][gate][col]  (bank = col: conflict-free)
  const int tid = threadIdx.x;
  const int jt = blockIdx.x << 5;    // j tile base
  const int bm = blockIdx.y << 4;    // batch tile base
  // compute mapping: 2 rows x 1 col x 4 gates per thread
  const int col = tid & 31;
  const int rp = (tid >> 5) << 1;    // 0,2,...,14
  // h load mapping: float2 each
  const int hr = tid >> 4;           // 0..15
  const int hk = (tid & 15) << 1;    // 0..30 step 2
  // w load mapping: 128 rows x 32 k, each thread 16 floats (4 x float4)
  const int wrow = tid & 127;
  const int wg = wrow >> 5;          // gate 0..3
  const int wc = wrow & 31;          // col 0..31
  const int wk = (tid >> 7) << 4;    // 0 or 16
  const float* wbase = whh + (size_t)(wg * HH + jt + wc) * HH + wk;
  const float* hbase = hprev + (size_t)(bm + hr) * pstride + hk;

  float acc[4][2] = {};
  for (int k0 = 0; k0 < HH; k0 += 32) {
    const float2 hv = *(const float2*)(hbase + k0);
    const float4 wv0 = *(const float4*)(wbase + k0);
    const float4 wv1 = *(const float4*)(wbase + k0 + 4);
    const float4 wv2 = *(const float4*)(wbase + k0 + 8);
    const float4 wv3 = *(const float4*)(wbase + k0 + 12);
    __syncthreads();
    hs[hk][hr] = hv.x; hs[hk + 1][hr] = hv.y;
    {
      const float wvv[16] = {wv0.x, wv0.y, wv0.z, wv0.w, wv1.x, wv1.y, wv1.z, wv1.w,
                             wv2.x, wv2.y, wv2.z, wv2.w, wv3.x, wv3.y, wv3.z, wv3.w};
#pragma unroll
      for (int i = 0; i < 16; ++i) wsm[wk + i][wg][wc] = wvv[i];
    }
    __syncthreads();
#pragma unroll
    for (int k = 0; k < 32; ++k) {
      const float2 a = *(const float2*)&hs[k][rp];
      const float wi = wsm[k][0][col];
      const float wf = wsm[k][1][col];
      const float wg_ = wsm[k][2][col];
      const float wo = wsm[k][3][col];
      acc[0][0] += a.x * wi;  acc[0][1] += a.y * wi;
      acc[1][0] += a.x * wf;  acc[1][1] += a.y * wf;
      acc[2][0] += a.x * wg_; acc[2][1] += a.y * wg_;
      acc[3][0] += a.x * wo;  acc[3][1] += a.y * wo;
    }
  }
#pragma unroll
  for (int rr = 0; rr < 2; ++rr) {
    const int b = bm + rp + rr;
    const int j = jt + col;
    const size_t gxo = (size_t)b * gxstride + j;
    const float gi = acc[0][rr] + gx[gxo];
    const float gf = acc[1][rr] + gx[gxo + HH];
    const float gg = acc[2][rr] + gx[gxo + 2 * HH];
    const float go = acc[3][rr] + gx[gxo + 3 * HH];
    const float si = 1.f / (1.f + expf(-gi));
    const float sf = 1.f / (1.f + expf(-gf));
    const float so = 1.f / (1.f + expf(-go));
    const size_t cidx = (size_t)b * HH + j;
    const float cn = sf * cbuf[cidx] + si * tanhf(gg);
    cbuf[cidx] = cn;
    hnext[(size_t)b * nstride + j] = so * tanhf(cn);
  }
}

// ------------------------------------------------------------------
// FC: out[b][n] = h_last[b] . fc_w[n] + fc_b[n].  One wave per output.
// ------------------------------------------------------------------
__global__ __launch_bounds__(256)
void fc_kernel(const float* __restrict__ hlast, const float* __restrict__ fcw,
               const float* __restrict__ fcb, float* __restrict__ out) {
  const int gw = (int)((blockIdx.x * 256 + threadIdx.x) >> 6);
  const int lane = threadIdx.x & 63;
  const int b = gw / CO;
  const int n = gw - b * CO;
  const float* hp = hlast + (size_t)b * HH;
  const float* wp = fcw + (size_t)n * HH;
  float s = 0.f;
  for (int k = lane; k < HH; k += 64) s += hp[k] * wp[k];
#pragma unroll
  for (int off = 32; off; off >>= 1) s += __shfl_down(s, off);
  if (lane == 0) out[b * CO + n] = s + fcb[n];
}

extern "C" void kernel_launch(void* const* d_in, const int* in_sizes, int n_in,
                              void* d_out, int out_size, void* d_ws, size_t ws_size,
                              hipStream_t stream) {
  const float* x    = (const float*)d_in[0];
  const float* wih0 = (const float*)d_in[1];
  const float* whh0 = (const float*)d_in[2];
  const float* bih0 = (const float*)d_in[3];
  const float* bhh0 = (const float*)d_in[4];
  const float* wih1 = (const float*)d_in[5];
  const float* whh1 = (const float*)d_in[6];
  const float* bih1 = (const float*)d_in[7];
  const float* bhh1 = (const float*)d_in[8];
  const float* fcw  = (const float*)d_in[9];
  const float* fcb  = (const float*)d_in[10];
  float* out = (float*)d_out;

  // Adaptive chunk size: largest power-of-two Tc whose scratch fits ws_size.
  // need(Tc) = [B*Tc*4H (gx) + B*Tc*H (h-chunk) + 4*B*H + H] floats
  int Tc = 64, lt = 6;
  while (Tc > 1) {
    size_t need = ((size_t)655360 * (size_t)Tc + 4u * 131072u + 1024u) * 4u;
    if (need <= ws_size) break;
    Tc >>= 1; --lt;
  }

  float* ws  = (float*)d_ws;
  float* gxc = ws;                                  // B*Tc*4H   [b][tl][4H]
  float* hc  = gxc + (size_t)BB * Tc * G4H;         // B*Tc*H    [b][tl][H]
  float* c0  = hc + (size_t)BB * Tc * HH;           // B*H
  float* c1  = c0 + (size_t)BB * HH;                // B*H
  float* h2a = c1 + (size_t)BB * HH;                // B*H
  float* h2b = h2a + (size_t)BB * HH;               // B*H
  float* zb  = h2b + (size_t)BB * HH;               // H zero row

  hipMemsetAsync(zb, 0, HH * sizeof(float), stream);
  hipMemsetAsync(c0, 0, (size_t)BB * HH * sizeof(float), stream);
  hipMemsetAsync(c1, 0, (size_t)BB * HH * sizeof(float), stream);

  const dim3 gGemm(G4H / 64, (BB * Tc) / 64);
  const dim3 gStep(HH / 32, BB / 16);
  const long long gxs = (long long)Tc * G4H;   // gx row stride (per b)
  const long long hcs = (long long)Tc * HH;    // h-chunk row stride (per b)

  const int nChunks = TT / Tc;
  for (int ci = 0; ci < nChunks; ++ci) {
    const int t0 = ci * Tc;

    // layer-0 input GEMM for this chunk: rows r=b*Tc+tl -> x[b][t0+tl][:]
    gemm_bias<<<gGemm, 256, 0, stream>>>(x + (size_t)t0 * DD, (long long)TT * DD,
                                         (long long)DD, lt, wih0, bih0, bhh0,
                                         gxc, G4H, DD);

    // layer-0 recurrence over the chunk; h written into hc[tl]
    for (int tl = 0; tl < Tc; ++tl) {
      const int t = t0 + tl;
      const float* hprev;
      long long ps;
      if (t == 0) { hprev = zb; ps = 0; }
      else {
        const int ptl = (tl == 0) ? (Tc - 1) : (tl - 1);  // prev chunk's last is intact
        hprev = hc + (size_t)ptl * HH; ps = hcs;
      }
      lstm_step<<<gStep, 256, 0, stream>>>(gxc + (size_t)tl * G4H, gxs, whh0,
                                           hprev, ps, hc + (size_t)tl * HH, hcs, c0);
    }

    // layer-1 input GEMM for this chunk (gxc reusable: already consumed)
    gemm_bias<<<gGemm, 256, 0, stream>>>(hc, hcs, (long long)HH, lt,
                                         wih1, bih1, bhh1, gxc, G4H, HH);

    // layer-1 recurrence over the chunk; ping-pong h2 buffers
    for (int tl = 0; tl < Tc; ++tl) {
      const int t = t0 + tl;
      const float* hprev;
      long long ps;
      if (t == 0) { hprev = zb; ps = 0; }
      else { hprev = ((t - 1) & 1) ? h2b : h2a; ps = HH; }
      float* hnext = (t & 1) ? h2b : h2a;
      lstm_step<<<gStep, 256, 0, stream>>>(gxc + (size_t)tl * G4H, gxs, whh1,
                                           hprev, ps, hnext, HH, c1);
    }
  }

  // final FC on h2 at t = TT-1 (odd -> h2b)
  fc_kernel<<<dim3((BB * CO * 64) / 256), 256, 0, stream>>>(h2b, fcw, fcb, out);
}